// Round 4
// baseline (429.671 us; speedup 1.0000x reference)
//
#include <hip/hip_runtime.h>
#include <stdint.h>
#include <math.h>

// ---- problem constants ----
#define NB 32
#define NH 256
#define NW 256
#define HW 65536
#define NJ 8
#define NCHAN 9           // 1 det channel + 8 joint channels per batch
#define NCH 288           // NB * NCHAN
#define TOPK 100
#define THRESH_C 0.1f
#define NEG_C (-10000.0f)
#define SDC 7168          // LDS survivor cap (mean ~7281 -> ~100-400 spill typical)
#define SPILL_CAP 4096    // global spill per channel (exactness fallback)

// ---- output layout (float offsets), concat of reference return tuple ----
#define OUT_BBOX  0       // (32,100,4)   12800
#define OUT_SCORE 12800   // (32,100,1)    3200
#define OUT_KPS   16000   // (32,100,16)  51200
#define OUT_CLS   67200   // (32,100,1)    3200
#define OUT_SCALE 70400   // (32,100,3)    9600
#define OUT_DISP  80000   // (32,100,16)  51200
#define OUT_HEAT  131200  // (32,100,16)  51200
// total 182400

// monotone float->uint key (order-preserving, incl. negatives)
__device__ __forceinline__ uint32_t flip_key(uint32_t b) {
    return (b & 0x80000000u) ? ~b : (b | 0x80000000u);
}
__device__ __forceinline__ float key_to_float(uint32_t k) {
    uint32_t b = (k & 0x80000000u) ? (k & 0x7FFFFFFFu) : ~k;
    return __uint_as_float(b);
}
__device__ __forceinline__ float sigmoidf_(float x) {
    return 1.0f / (1.0f + expf(-x));
}

// Fused streaming NMS + exact top-K. One block per channel; the channel's
// 256x256 map is read from HBM exactly once (1 KB/row/wave float4 loads).
// Separable NMS: hmax[y][x] = max(row[y][x-1..x+1]); survivor iff
// v >= max(hmax[ym], hmax[y], hmax[yp]) — identical to the 3x3 clamped max.
// Survivors (flip_key(v), pix) go to LDS (cap SDC) with an exact global
// spill path; then byte-radix select + tie resolution + bitonic sort, all
// in-block. LDS ~79 KB -> 2 blocks/CU -> all 288 blocks co-resident.
__global__ void __launch_bounds__(256, 1) nms_topk(
        const float* __restrict__ hm, const float* __restrict__ hm_hp,
        uint2* __restrict__ spill_g,
        float* __restrict__ det_score, int* __restrict__ det_ind,
        float* __restrict__ hp_score, int* __restrict__ hp_ind) {
    int ch = blockIdx.x;
    int b = ch / NCHAN, c = ch % NCHAN;
    const float* __restrict__ src = (c == 0)
        ? (hm + (size_t)b * HW)
        : (hm_hp + ((size_t)b * NJ + (c - 1)) * HW);
    uint2* __restrict__ spill = spill_g + (size_t)ch * SPILL_CAP;

    __shared__ float vbuf[8][256];     // 8 KB  value ring (8 rows)
    __shared__ float hbuf[8][256];     // 8 KB  hmax ring
    __shared__ uint2 sdat[SDC];        // 56 KB survivors
    __shared__ uint32_t hist[256];
    __shared__ uint2 cand[TOPK];
    __shared__ uint32_t tieIdx[512];
    __shared__ uint64_t keys[128];
    __shared__ int scnt, gcnt, tcnt, sKrem;
    __shared__ uint32_t sMask, sPref;

    int w    = threadIdx.x >> 6;       // wave id 0..3 (one row per wave)
    int lane = threadIdx.x & 63;       // 64 col-groups of 4 px

    // --- helpers as lambdas ---
    auto store_ring = [&](int r, float4 cv) {
        float hl = __shfl(cv.w, (lane + 63) & 63);
        float hr = __shfl(cv.x, (lane + 1) & 63);
        if (lane == 0)  hl = cv.x;     // x=0 clamps to itself
        if (lane == 63) hr = cv.w;     // x=255 clamps to itself
        float4 h;
        h.x = fmaxf(hl,   fmaxf(cv.x, cv.y));
        h.y = fmaxf(cv.x, fmaxf(cv.y, cv.z));
        h.z = fmaxf(cv.y, fmaxf(cv.z, cv.w));
        h.w = fmaxf(cv.z, fmaxf(cv.w, hr));
        ((float4*)vbuf[r & 7])[lane] = cv;
        ((float4*)hbuf[r & 7])[lane] = h;
    };
    auto nms_row = [&](int y) {
        int sm = ((y > 0) ? y - 1 : 0) & 7;
        int sc = y & 7;
        int sp = ((y < NH - 1) ? y + 1 : NH - 1) & 7;
        float4 v  = ((float4*)vbuf[sc])[lane];
        float4 hc = ((float4*)hbuf[sc])[lane];
        float4 ha = ((float4*)hbuf[sm])[lane];
        float4 hb = ((float4*)hbuf[sp])[lane];
        bool s0 = v.x >= fmaxf(ha.x, fmaxf(hc.x, hb.x));
        bool s1 = v.y >= fmaxf(ha.y, fmaxf(hc.y, hb.y));
        bool s2 = v.z >= fmaxf(ha.z, fmaxf(hc.z, hb.z));
        bool s3 = v.w >= fmaxf(ha.w, fmaxf(hc.w, hb.w));
        int cnt = (int)s0 + (int)s1 + (int)s2 + (int)s3;
        if (cnt) {
            int pos = atomicAdd(&scnt, cnt);
            int rowoff = y * NW + 4 * lane;
            float vv[4] = {v.x, v.y, v.z, v.w};
            bool sv[4] = {s0, s1, s2, s3};
#pragma unroll
            for (int i = 0; i < 4; ++i) {
                if (sv[i]) {
                    uint2 e = make_uint2(flip_key(__float_as_uint(vv[i])),
                                         (unsigned)(rowoff + i));
                    if (pos < SDC) sdat[pos] = e;
                    else { int q = pos - SDC; if (q < SPILL_CAP) spill[q] = e; }
                    ++pos;
                }
            }
        }
    };

    // --- streaming NMS over 64 chunks of 4 rows ---
    if (threadIdx.x == 0) scnt = 0;
    float4 c0 = ((const float4*)(src + (size_t)w * NW))[lane];   // chunk 0
    store_ring(w, c0);
    __syncthreads();
    for (int t = 0; t < 64; ++t) {
        float4 cn;
        int rn = 4 * (t + 1) + w;
        if (t < 63) cn = ((const float4*)(src + (size_t)rn * NW))[lane];
        int y = 4 * t - 1 + w;            // rows 4t-1 .. 4t+2 this iter
        if (y >= 0) nms_row(y);
        __syncthreads();                  // ring reads done before overwrite
        if (t < 63) store_ring(rn, cn);
        __syncthreads();                  // ring writes visible to next reads
    }
    if (w == 0) nms_row(255);             // tail row (ring rows 248..255 intact)
    __syncthreads();

    int total = scnt;
    int nl = (total < SDC) ? total : SDC;
    int ns = total - SDC; if (ns < 0) ns = 0; if (ns > SPILL_CAP) ns = SPILL_CAP;

    // --- byte-radix select (exact threshold key T + count of remainder) ---
    if (threadIdx.x == 0) { sKrem = TOPK; sMask = 0; sPref = 0; }
    __syncthreads();
    for (int shift = 24; shift >= 0; shift -= 8) {
        for (int i = threadIdx.x; i < 256; i += 256) hist[i] = 0;
        __syncthreads();
        uint32_t pm = sMask, pv = sPref;
        for (int i = threadIdx.x; i < nl; i += 256) {
            uint32_t vb = sdat[i].x;
            if ((vb & pm) == pv) atomicAdd(&hist[(vb >> shift) & 0xFF], 1u);
        }
        for (int i = threadIdx.x; i < ns; i += 256) {
            uint32_t vb = spill[i].x;
            if ((vb & pm) == pv) atomicAdd(&hist[(vb >> shift) & 0xFF], 1u);
        }
        __syncthreads();
        if (threadIdx.x == 0) {
            int rem = sKrem, cum = 0, bin = 255;
            for (; bin >= 0; --bin) {
                int h = (int)hist[bin];
                if (cum + h >= rem) break;
                cum += h;
            }
            if (bin < 0) bin = 0;
            sKrem = rem - cum;
            sPref = pv | ((uint32_t)bin << shift);
            sMask = pm | (0xFFu << shift);
        }
        __syncthreads();
    }
    uint32_t T = sPref;
    int tiesNeeded = sKrem;               // >= 1
    if (threadIdx.x == 0) { gcnt = 0; tcnt = 0; }
    __syncthreads();
    for (int i = threadIdx.x; i < nl; i += 256) {
        uint2 e = sdat[i];
        if (e.x > T) { int p = atomicAdd(&gcnt, 1); if (p < TOPK) cand[p] = e; }
        else if (e.x == T) { int p = atomicAdd(&tcnt, 1); if (p < 512) tieIdx[p] = e.y; }
    }
    for (int i = threadIdx.x; i < ns; i += 256) {
        uint2 e = spill[i];
        if (e.x > T) { int p = atomicAdd(&gcnt, 1); if (p < TOPK) cand[p] = e; }
        else if (e.x == T) { int p = atomicAdd(&tcnt, 1); if (p < 512) tieIdx[p] = e.y; }
    }
    __syncthreads();
    int g  = min(gcnt, TOPK);             // == TOPK - tiesNeeded by construction
    int tc = min(tcnt, 512);

    for (int i = threadIdx.x; i < 128; i += 256) keys[i] = 0;
    __syncthreads();
    for (int i = threadIdx.x; i < g; i += 256)
        keys[i] = ((uint64_t)cand[i].x << 32) | (uint64_t)(0xFFFFFFFFu - cand[i].y);
    // tie entries: take the tiesNeeded smallest indices (jax lower-index-first)
    for (int i = threadIdx.x; i < tc; i += 256) {
        uint32_t my = tieIdx[i];
        int r = 0;
        for (int m2 = 0; m2 < tc; ++m2) r += (tieIdx[m2] < my) ? 1 : 0;
        if (r < tiesNeeded)
            keys[g + r] = ((uint64_t)T << 32) | (uint64_t)(0xFFFFFFFFu - my);
    }
    __syncthreads();

    // bitonic sort 128 keys descending (composite: value desc, index asc)
    for (int len = 2; len <= 128; len <<= 1) {
        for (int stride = len >> 1; stride > 0; stride >>= 1) {
            int i = threadIdx.x;
            if (i < 128) {
                int j2 = i ^ stride;
                if (j2 > i) {
                    uint64_t a = keys[i], c2 = keys[j2];
                    bool desc = ((i & len) == 0);
                    bool sw = desc ? (a < c2) : (a > c2);
                    if (sw) { keys[i] = c2; keys[j2] = a; }
                }
            }
            __syncthreads();
        }
    }

    for (int k = threadIdx.x; k < TOPK; k += 256) {
        uint64_t key = keys[k];
        float raw = key_to_float((uint32_t)(key >> 32));
        int idx = (int)(0xFFFFFFFFu - (uint32_t)key);
        float s = sigmoidf_(raw);
        if (c == 0) { det_score[b * TOPK + k] = s; det_ind[b * TOPK + k] = idx; }
        else {
            int o = (b * NJ + (c - 1)) * TOPK + k;
            hp_score[o] = s; hp_ind[o] = idx;
        }
    }
}

// fused tail: kp candidates + det decode + joint assignment. One block per
// batch image; all intermediates (candidates, bboxes, disp, scores) in LDS.
__global__ void decode_tail(const float* __restrict__ wh, const float* __restrict__ kps,
                            const float* __restrict__ reg, const float* __restrict__ scale,
                            const float* __restrict__ hp_offset,
                            const float* __restrict__ det_score, const int* __restrict__ det_ind,
                            const float* __restrict__ hp_score, const int* __restrict__ hp_ind,
                            float* __restrict__ out) {
    int b = blockIdx.x;
    __shared__ float sx[NJ * TOPK], sy[NJ * TOPK], ss[NJ * TOPK];
    __shared__ float kd[TOPK * 16];      // kps_displacement (also OUT_DISP)
    __shared__ float sbb[TOPK * 4];      // bboxes
    __shared__ float ssc[TOPK];          // det scores

    // phase 1: heatmap keypoint candidates (800 per image)
    for (int i = threadIdx.x; i < NJ * TOPK; i += blockDim.x) {
        int t = b * NJ * TOPK + i;
        int ind = hp_ind[t];
        float sc = hp_score[t];
        float x = (float)(ind & 255) + hp_offset[((size_t)b * 2 + 0) * HW + ind];
        float y = (float)(ind >> 8)  + hp_offset[((size_t)b * 2 + 1) * HW + ind];
        bool m = sc > THRESH_C;
        ss[i] = m ? sc : -1.0f;
        sx[i] = m ? x  : NEG_C;
        sy[i] = m ? y  : NEG_C;
    }
    // phase 2a: kps displacement gathers (800 pairs)
    for (int i = threadIdx.x; i < TOPK * NJ; i += blockDim.x) {
        int k = i >> 3, j = i & 7;
        int ind = det_ind[b * TOPK + k];
        float xs = (float)(ind & 255), ys = (float)(ind >> 8);
        kd[k * 16 + 2 * j]     = kps[((size_t)b * 16 + 2 * j)     * HW + ind] + xs;
        kd[k * 16 + 2 * j + 1] = kps[((size_t)b * 16 + 2 * j + 1) * HW + ind] + ys;
    }
    // phase 2b: bbox/score/cls/scale (100 dets)
    for (int k = threadIdx.x; k < TOPK; k += blockDim.x) {
        int tid2 = b * TOPK + k;
        int ind = det_ind[tid2];
        float xs = (float)(ind & 255), ys = (float)(ind >> 8);
        float xr = xs + reg[((size_t)b * 2 + 0) * HW + ind];
        float yr = ys + reg[((size_t)b * 2 + 1) * HW + ind];
        float w0 = wh[((size_t)b * 2 + 0) * HW + ind];
        float w1 = wh[((size_t)b * 2 + 1) * HW + ind];
        float x0 = xr - w0 * 0.5f, y0 = yr - w1 * 0.5f;
        float x1 = xr + w0 * 0.5f, y1 = yr + w1 * 0.5f;
        sbb[k * 4 + 0] = x0; sbb[k * 4 + 1] = y0; sbb[k * 4 + 2] = x1; sbb[k * 4 + 3] = y1;
        float* bb = out + OUT_BBOX + (size_t)tid2 * 4;
        bb[0] = x0; bb[1] = y0; bb[2] = x1; bb[3] = y1;
        float sc = det_score[tid2];
        ssc[k] = sc;
        out[OUT_SCORE + tid2] = sc;
        out[OUT_CLS + tid2] = 0.0f;      // clses = ind // K over c=1 -> always 0
        float* os = out + OUT_SCALE + (size_t)tid2 * 3;
        os[0] = scale[((size_t)b * 3 + 0) * HW + ind];
        os[1] = scale[((size_t)b * 3 + 1) * HW + ind];
        os[2] = scale[((size_t)b * 3 + 2) * HW + ind];
    }
    __syncthreads();
    // write disp from LDS (coalesced)
    for (int i = threadIdx.x; i < TOPK * 16; i += blockDim.x)
        out[OUT_DISP + (size_t)b * TOPK * 16 + i] = kd[i];

    // phase 3: joint assignment (800 work items)
    for (int w = threadIdx.x; w < TOPK * NJ; w += blockDim.x) {
        int k = w >> 3, j = w & 7;
        int tk = b * TOPK + k;
        float kx = kd[k * 16 + 2 * j];
        float ky = kd[k * 16 + 2 * j + 1];
        float x0 = sbb[k * 4 + 0], y0 = sbb[k * 4 + 1];
        float x1 = sbb[k * 4 + 2], y1 = sbb[k * 4 + 3];
        float best = 1e30f; int bl = 0;
        for (int l = 0; l < TOPK; ++l) {
            float dx = kx - sx[j * TOPK + l];
            float dy = ky - sy[j * TOPK + l];
            float dist = sqrtf(dx * dx + dy * dy);
            if (dist < best) { best = dist; bl = l; }  // strict <: first-min == argmin
        }
        float hx = sx[j * TOPK + bl], hy = sy[j * TOPK + bl], hs = ss[j * TOPK + bl];
        float diag = fmaxf(y1 - y0, x1 - x0);
        bool mask = (hx < x0) || (hx > x1) || (hy < y0) || (hy > y1) ||
                    (hs < THRESH_C) || (best > diag * 0.3f);
        out[OUT_KPS + (size_t)tk * 16 + 2 * j]     = mask ? kx : hx;
        out[OUT_KPS + (size_t)tk * 16 + 2 * j + 1] = mask ? ky : hy;
        float sc = ssc[k];
        bool mask2 = (hx > 0.8f * x0) && (hx < 1.2f * x1) && (hy > 0.8f * y0) &&
                     (hy < 1.2f * y1) && (hs > THRESH_C) && (best < diag * 0.5f) &&
                     (sc > THRESH_C);
        float fx = mask2 ? hx : NEG_C;
        float fy = mask2 ? hy : NEG_C;
        bool valid = (fx != NEG_C) && (fy != NEG_C);
        out[OUT_HEAT + (size_t)tk * 16 + 2 * j]     = valid ? fx : NEG_C;
        out[OUT_HEAT + (size_t)tk * 16 + 2 * j + 1] = valid ? fy : NEG_C;
    }
}

extern "C" void kernel_launch(void* const* d_in, const int* in_sizes, int n_in,
                              void* d_out, int out_size, void* d_ws, size_t ws_size,
                              hipStream_t stream) {
    const float* hm        = (const float*)d_in[0];
    const float* wh        = (const float*)d_in[1];
    const float* kps       = (const float*)d_in[2];
    const float* reg       = (const float*)d_in[3];
    const float* hm_hp     = (const float*)d_in[4];
    const float* hp_offset = (const float*)d_in[5];
    const float* scale     = (const float*)d_in[6];
    float* out = (float*)d_out;
    char* ws = (char*)d_ws;

    // workspace layout (bytes); spill region needs no zeroing (block-local counts)
    float* det_score = (float*)(ws + 0);        // 3200 f
    int*   det_ind   = (int*)(ws + 12800);      // 3200 i
    float* hp_score  = (float*)(ws + 25600);    // 25600 f
    int*   hp_ind    = (int*)(ws + 128000);     // 25600 i
    uint2* spill     = (uint2*)(ws + 230400);   // 288*4096*8 = 9.4 MB

    nms_topk<<<NCH, 256, 0, stream>>>(hm, hm_hp, spill,
                                      det_score, det_ind, hp_score, hp_ind);
    decode_tail<<<NB, 256, 0, stream>>>(wh, kps, reg, scale, hp_offset,
                                        det_score, det_ind, hp_score, hp_ind, out);
}